// Round 10
// baseline (496.414 us; speedup 1.0000x reference)
//
#include <hip/hip_runtime.h>
#include <hip/hip_bf16.h>

#define N_NODES 100000
#define N_EDGES 3200000
#define D 256

// ---- buckets: 64 rows each ----
#define RSH3 6
#define RPB3 64
#define NB3 ((N_NODES + RPB3 - 1) / RPB3)          // 1563
// ---- fill chunking: 1024 blocks = exactly 4/CU, 32 waves/CU ----
#define FILL_CH 3125                                // edges per fill block (1024*3125 = 3.2M exactly)
#define NBLK_F 1024
#define REC_STRIDE 3126                             // even -> 16B-aligned block rows
#define CLOC_W (NB3 + 1)                            // 1564
// ---- fused sort+aggregate caps ----
#define RCAP 12                                     // recs/thread in regs
#define SCAP 3072                                   // = RCAP*256; sorted LDS capacity
#define OCAP 64                                     // overflow side-buffer

typedef __attribute__((ext_vector_type(8))) short short8;   // 8 bf16 (4 VGPRs)
typedef __attribute__((ext_vector_type(4))) float floatx4;  // MFMA C/D

__device__ __forceinline__ unsigned short f32_to_bf16_rne(float f) {
    unsigned int u = __float_as_uint(f);
    u += 0x7FFFu + ((u >> 16) & 1u);
    return (unsigned short)(u >> 16);
}
__device__ __forceinline__ float bf16_bits_to_f32(unsigned short b) {
    return __uint_as_float(((unsigned int)b) << 16);
}
__device__ __forceinline__ float blo(unsigned int x) { return __uint_as_float(x << 16); }
__device__ __forceinline__ float bhi(unsigned int x) { return __uint_as_float(x & 0xFFFF0000u); }

// ---------------- W (fp32 [K][N]) -> bf16 MFMA-B-fragment order --------------
__global__ __launch_bounds__(256) void convert_w_k(const float* __restrict__ w,
                                                   unsigned short* __restrict__ wsw) {
    int t = blockIdx.x * 256 + threadIdx.x;
    int j     = t & 7;
    int lane  = (t >> 3) & 63;
    int kstep = (t >> 9) & 7;
    int ntile = t >> 12;
    int k = kstep * 32 + (lane >> 4) * 8 + j;
    int n = ntile * 16 + (lane & 15);
    wsw[t] = f32_to_bf16_rne(w[k * D + n]);
}

// ---------------- xw = x @ W (bf16 MFMA), output bf16 ------------------------
__global__ __launch_bounds__(512) void gemm_xw_k(const float* __restrict__ x,
                                                 const unsigned short* __restrict__ wsw,
                                                 unsigned short* __restrict__ xwb) {
    __shared__ uint4 wlds[8192];  // 128 KiB swizzled bf16 W
    const int tid = threadIdx.x;
#pragma unroll
    for (int i = 0; i < 16; ++i) {
        int idx = i * 512 + tid;
        wlds[idx] = ((const uint4*)wsw)[idx];
    }
    __syncthreads();

    const int lane = tid & 63;
    const int wave = tid >> 6;            // 0..7
    const int q    = lane >> 4;
    const int ml   = lane & 15;
    const long rowBase = (long)blockIdx.x * 128 + wave * 16;
    long arow = rowBase + ml;
    if (arow >= N_NODES) arow = 0;
    const float* xr = x + arow * (long)D;

    floatx4 acc[16];
#pragma unroll
    for (int i = 0; i < 16; ++i) acc[i] = (floatx4){0.f, 0.f, 0.f, 0.f};

    const short8* wfrag = (const short8*)wlds;

#pragma unroll
    for (int ks = 0; ks < 8; ++ks) {
        const float4 a0 = *(const float4*)(xr + ks * 32 + q * 8);
        const float4 a1 = *(const float4*)(xr + ks * 32 + q * 8 + 4);
        short8 af;
        af[0] = (short)f32_to_bf16_rne(a0.x);
        af[1] = (short)f32_to_bf16_rne(a0.y);
        af[2] = (short)f32_to_bf16_rne(a0.z);
        af[3] = (short)f32_to_bf16_rne(a0.w);
        af[4] = (short)f32_to_bf16_rne(a1.x);
        af[5] = (short)f32_to_bf16_rne(a1.y);
        af[6] = (short)f32_to_bf16_rne(a1.z);
        af[7] = (short)f32_to_bf16_rne(a1.w);
#pragma unroll
        for (int nt = 0; nt < 16; ++nt) {
            acc[nt] = __builtin_amdgcn_mfma_f32_16x16x32_bf16(
                af, wfrag[(nt * 8 + ks) * 64 + lane], acc[nt], 0, 0, 0);
        }
    }

#pragma unroll
    for (int nt = 0; nt < 16; ++nt) {
#pragma unroll
        for (int r = 0; r < 4; ++r) {
            long orow = rowBase + q * 4 + r;
            if (orow < N_NODES)
                xwb[orow * (long)D + nt * 16 + ml] = f32_to_bf16_rne(acc[nt][r]);
        }
    }
}

// ---------------- single-kernel build: LDS-staged sort, block-major ----------
// 1024 blocks x 37.6 KB LDS = exactly 4 blocks/CU -> 32 waves/CU (HW max),
// double the latency-hiding of the prior 2/CU version for the same op count.
__global__ __launch_bounds__(512, 8) void bfill_k(const int* __restrict__ erow,
                                                  const int* __restrict__ ecol,
                                                  const float* __restrict__ eval,
                                                  int* __restrict__ Cloc,
                                                  unsigned long long* __restrict__ recs) {
    __shared__ unsigned long long lrec[FILL_CH];   // 25 KB
    __shared__ int h[NB3];                          // 6.25 KB
    __shared__ int cur[NB3];                        // 6.25 KB
    __shared__ int wsum[8];
    const int tid = threadIdx.x;
    const int blk = blockIdx.x;
    const int s = blk * FILL_CH;
    const int e = min(s + FILL_CH, N_EDGES);
    const int n = e - s;

    for (int i = tid; i < NB3; i += 512) h[i] = 0;
    __syncthreads();

    // bucket histogram
    for (int i = s + tid; i < e; i += 512) atomicAdd(&h[erow[i] >> RSH3], 1);
    __syncthreads();

    // scan NB3 bins (4/thread) -> cur (local excl prefix) + write Cloc row
    {
        const int b0 = 4 * tid;
        int v0 = (b0     < NB3) ? h[b0]     : 0;
        int v1 = (b0 + 1 < NB3) ? h[b0 + 1] : 0;
        int v2 = (b0 + 2 < NB3) ? h[b0 + 2] : 0;
        int v3 = (b0 + 3 < NB3) ? h[b0 + 3] : 0;
        int s4 = v0 + v1 + v2 + v3;
        const int lane = tid & 63;
        const int wv = tid >> 6;
        int x = s4;
#pragma unroll
        for (int d = 1; d < 64; d <<= 1) {
            int u = __shfl_up(x, d);
            if (lane >= d) x += u;
        }
        if (lane == 63) wsum[wv] = x;
        __syncthreads();
        if (wv == 0) {
            int y = (lane < 8) ? wsum[lane] : 0;
#pragma unroll
            for (int d = 1; d < 8; d <<= 1) {
                int u = __shfl_up(y, d);
                if (lane >= d) y += u;
            }
            if (lane < 8) wsum[lane] = y;
        }
        __syncthreads();
        int excl = x - s4 + ((wv > 0) ? wsum[wv - 1] : 0);
        int* crow = Cloc + (size_t)blk * CLOC_W;
        if (b0     < NB3) { cur[b0]     = excl;                crow[b0]     = excl; }
        if (b0 + 1 < NB3) { cur[b0 + 1] = excl + v0;           crow[b0 + 1] = excl + v0; }
        if (b0 + 2 < NB3) { cur[b0 + 2] = excl + v0 + v1;      crow[b0 + 2] = excl + v0 + v1; }
        if (b0 + 3 < NB3) { cur[b0 + 3] = excl + v0 + v1 + v2; crow[b0 + 3] = excl + v0 + v1 + v2; }
        if (tid == 0) crow[NB3] = n;
    }
    __syncthreads();

    // scatter into LDS (bucket-sorted within block)
    for (int i = s + tid; i < e; i += 512) {
        int r = erow[i];
        int b = r >> RSH3;
        unsigned long long rec =
            ((unsigned long long)(r & (RPB3 - 1)) << 33) |
            ((unsigned long long)f32_to_bf16_rne(eval[i]) << 17) |
            (unsigned int)ecol[i];
        int pos = atomicAdd(&cur[b], 1);
        lrec[pos] = rec;
    }
    __syncthreads();

    // flush: vectorized (2 recs per op), full lines, private region
    unsigned long long* grow = recs + (size_t)blk * REC_STRIDE;
    {
        const uint4* lv = (const uint4*)lrec;
        uint4* gv = (uint4*)grow;                  // 16B-aligned: REC_STRIDE even
        const int np = n >> 1;
        for (int i = tid; i < np; i += 512) gv[i] = lv[i];
        if ((n & 1) && tid == 0) grow[n - 1] = lrec[n - 1];
    }
}

// ---------------- transpose Cloc (u32 [NBLK_F][CLOC_W]) -> Ctr u16 -----------
#define TRT_B ((CLOC_W + 63) / 64)                  // 25
#define TRT_K (NBLK_F / 64)                         // 16
__global__ __launch_bounds__(256) void tr_k(const int* __restrict__ Cloc,
                                            unsigned short* __restrict__ Ctr) {
    __shared__ unsigned short tile[64][65];
    const int bt = blockIdx.x % TRT_B;
    const int kt = blockIdx.x / TRT_B;
#pragma unroll
    for (int i = 0; i < 16; ++i) {
        int r = i * 4 + (threadIdx.x >> 6);          // row within blk-tile
        int c = threadIdx.x & 63;                    // col within b-tile
        int blk = kt * 64 + r;
        int b   = bt * 64 + c;
        tile[r][c] = (blk < NBLK_F && b < CLOC_W)
                         ? (unsigned short)Cloc[(size_t)blk * CLOC_W + b] : (unsigned short)0;
    }
    __syncthreads();
#pragma unroll
    for (int i = 0; i < 16; ++i) {
        int r = i * 4 + (threadIdx.x >> 6);          // row within b-tile -> Ctr row
        int c = threadIdx.x & 63;                    // col within blk-tile -> Ctr col
        int b   = bt * 64 + r;
        int blk = kt * 64 + c;
        if (b < CLOC_W && blk < NBLK_F)
            Ctr[(size_t)b * NBLK_F + blk] = tile[c][r];
    }
}

// ---------------- binary-search fallback (rare overflow path only) -----------
__device__ __forceinline__ unsigned long long fetch_rec(
    const unsigned long long* __restrict__ recs,
    const unsigned short* __restrict__ S,
    const unsigned short* __restrict__ P, int i) {
    int lo = 0, hi = NBLK_F;
#pragma unroll
    for (int it = 0; it < 10; ++it) {              // 1024 -> 1 in 10 halvings
        int mid = (lo + hi) >> 1;
        if ((int)P[mid] <= i) lo = mid; else hi = mid;
    }
    return recs[(size_t)lo * REC_STRIDE + (int)S[lo] + (i - (int)P[lo])];
}

// ---------------- fused per-bucket sort + segment reduce ---------------------
__global__ __launch_bounds__(256) void baggr_k(const unsigned short* __restrict__ xwb,
                                               const unsigned short* __restrict__ Ctr,
                                               const unsigned long long* __restrict__ recs,
                                               float* __restrict__ out) {
    __shared__ unsigned int   cols[SCAP];          // 12 KiB (scratch: index map, then sorted cols)
    __shared__ unsigned short vals[SCAP];          // 6 KiB
    __shared__ unsigned long long ovfl[OCAP];
    __shared__ unsigned short S[NBLK_F];           // 2 KiB
    __shared__ unsigned short L[NBLK_F];           // 2 KiB
    __shared__ unsigned short P[NBLK_F + 1];       // 2 KiB
    __shared__ int hist[RPB3];
    __shared__ int cur[RPB3];
    __shared__ int wsum4[4];
    __shared__ int novf;
    const int t = threadIdx.x;
    const int b = blockIdx.x;

    if (t < RPB3) hist[t] = 0;
    if (t == 0) novf = 0;
    // stage this bucket's run table: two contiguous u16 rows of Ctr
    {
        const unsigned short* Sb = Ctr + (size_t)b * NBLK_F;
        const unsigned short* Eb = Ctr + (size_t)(b + 1) * NBLK_F;
        for (int j = t; j < NBLK_F; j += 256) {
            unsigned short a = Sb[j];
            S[j] = a;
            L[j] = (unsigned short)(Eb[j] - a);
        }
    }
    __syncthreads();

    // scan run lengths -> P (exclusive), 4/thread over NBLK_F = 1024 entries
    {
        const int j0 = 4 * t;
        int v0 = (int)L[j0];
        int v1 = (int)L[j0 + 1];
        int v2 = (int)L[j0 + 2];
        int v3 = (int)L[j0 + 3];
        int s4 = v0 + v1 + v2 + v3;
        const int lane = t & 63;
        const int wv = t >> 6;
        int x = s4;
#pragma unroll
        for (int d = 1; d < 64; d <<= 1) {
            int u = __shfl_up(x, d);
            if (lane >= d) x += u;
        }
        if (lane == 63) wsum4[wv] = x;
        __syncthreads();
        if (wv == 0) {
            int y = (lane < 4) ? wsum4[lane] : 0;
#pragma unroll
            for (int d = 1; d < 4; d <<= 1) {
                int u = __shfl_up(y, d);
                if (lane >= d) y += u;
            }
            if (lane < 4) wsum4[lane] = y;
        }
        __syncthreads();
        int excl = x - s4 + ((wv > 0) ? wsum4[wv - 1] : 0);
        P[j0]     = (unsigned short)excl;
        P[j0 + 1] = (unsigned short)(excl + v0);
        P[j0 + 2] = (unsigned short)(excl + v0 + v1);
        P[j0 + 3] = (unsigned short)(excl + v0 + v1 + v2);
        if (t == 255) P[NBLK_F] = (unsigned short)(excl + s4);
    }
    __syncthreads();
    const int nfull = (int)P[NBLK_F];

    // build direct index map in cols[] scratch: cols[flat i] = rec index in recs
    for (int j = t; j < NBLK_F; j += 256) {
        int p = (int)P[j];
        int len = (int)L[j];
        unsigned int base = (unsigned int)(j * REC_STRIDE + (int)S[j]);
        for (int k = 0; k < len; ++k) {
            int pp = p + k;
            if (pp < SCAP) cols[pp] = base + k;
        }
    }
    __syncthreads();

    // load recs into regs via the map (1 LDS read + 1 global load each)
    unsigned long long myrec[RCAP];
#pragma unroll
    for (int k = 0; k < RCAP; ++k) {
        int i = k * 256 + t;                       // i < RCAP*256 == SCAP
        if (i < nfull) myrec[k] = recs[cols[i]];
    }
#pragma unroll
    for (int k = 0; k < RCAP; ++k) {
        int i = k * 256 + t;
        if (i < nfull) atomicAdd(&hist[(int)((myrec[k] >> 33) & 63u)], 1);
    }
    for (int i = SCAP + t; i < nfull; i += 256)    // never in practice
        atomicAdd(&hist[(int)((fetch_rec(recs, S, P, i) >> 33) & 63u)], 1);
    __syncthreads();

    // exclusive scan of 64 row bins (wave 0)
    if (t < 64) {
        int v = hist[t];
        int x = v;
#pragma unroll
        for (int d = 1; d < 64; d <<= 1) {
            int u = __shfl_up(x, d);
            if (t >= d) x += u;
        }
        cur[t] = x - v;
    }
    __syncthreads();

    // scatter into sorted split arrays (overwrites the cols[] scratch)
#pragma unroll
    for (int k = 0; k < RCAP; ++k) {
        int i = k * 256 + t;
        if (i < nfull) {
            unsigned long long rec = myrec[k];
            int rl = (int)((rec >> 33) & 63u);
            int pos = atomicAdd(&cur[rl], 1);
            if (pos < SCAP) {
                cols[pos] = (unsigned int)(rec & 0x1FFFFu);
                vals[pos] = (unsigned short)((rec >> 17) & 0xFFFFu);
            } else {
                int o = atomicAdd(&novf, 1);
                if (o < OCAP) ovfl[o] = rec;
            }
        }
    }
    for (int i = SCAP + t; i < nfull; i += 256) {  // never in practice
        unsigned long long rec = fetch_rec(recs, S, P, i);
        int rl = (int)((rec >> 33) & 63u);
        int pos = atomicAdd(&cur[rl], 1);
        if (pos < SCAP) {
            cols[pos] = (unsigned int)(rec & 0x1FFFFu);
            vals[pos] = (unsigned short)((rec >> 17) & 0xFFFFu);
        } else {
            int o = atomicAdd(&novf, 1);
            if (o < OCAP) ovfl[o] = rec;
        }
    }
    __syncthreads();

    const int wave = t >> 6;
    const int lane = t & 63;
    const int half = lane >> 5;
    const int hl   = lane & 31;
    const int nov  = min(novf, OCAP);

#pragma unroll 1
    for (int rr = 0; rr < 16; ++rr) {
        const int rl = wave * 16 + rr;
        const int r = (b << RSH3) + rl;
        if (r >= N_NODES) break;
        const int e_ = cur[rl];
        const int s_ = e_ - hist[rl];
        const int e = min(e_, SCAP);
        const int s = min(s_, SCAP);

        float acc[8];
#pragma unroll
        for (int k = 0; k < 8; ++k) acc[k] = 0.f;

#pragma unroll 1
        for (int jb = s; jb < e; jb += 64) {
            const int cnt = min(64, e - jb);
            const int pairs = (cnt + 1) >> 1;
            const int hp = cnt >> 1;
            int tt = 0;

#define FMA8(qv, bv)                                                           \
            acc[0] += bv * blo(qv.x); acc[1] += bv * bhi(qv.x);                \
            acc[2] += bv * blo(qv.y); acc[3] += bv * bhi(qv.y);                \
            acc[4] += bv * blo(qv.z); acc[5] += bv * bhi(qv.z);                \
            acc[6] += bv * blo(qv.w); acc[7] += bv * bhi(qv.w);
#define SLOTL(ss, qv, bv)                                                      \
            {                                                                  \
                int src = jb + 2 * (tt + (ss)) + half;                         \
                unsigned int bc = cols[src];                                   \
                bv = bf16_bits_to_f32(vals[src]);                              \
                qv = ((const uint4*)(xwb + (size_t)bc * D))[hl];               \
            }

            // ---- 8-deep unmasked fast path (16 edges / iter) ----
#pragma unroll 1
            for (; tt + 8 <= hp; tt += 8) {
                uint4 q0, q1, q2, q3, q4, q5, q6, q7;
                float b0, b1, b2, b3, b4, b5, b6, b7;
                SLOTL(0, q0, b0) SLOTL(1, q1, b1) SLOTL(2, q2, b2) SLOTL(3, q3, b3)
                SLOTL(4, q4, b4) SLOTL(5, q5, b5) SLOTL(6, q6, b6) SLOTL(7, q7, b7)
                FMA8(q0, b0) FMA8(q1, b1) FMA8(q2, b2) FMA8(q3, b3)
                FMA8(q4, b4) FMA8(q5, b5) FMA8(q6, b6) FMA8(q7, b7)
            }
            // ---- 4-deep unmasked (8 edges) ----
            if (tt + 4 <= hp) {
                uint4 q0, q1, q2, q3;
                float b0, b1, b2, b3;
                SLOTL(0, q0, b0) SLOTL(1, q1, b1) SLOTL(2, q2, b2) SLOTL(3, q3, b3)
                FMA8(q0, b0) FMA8(q1, b1) FMA8(q2, b2) FMA8(q3, b3)
                tt += 4;
            }
#undef SLOTL
            // ---- masked scalar-pair tail ----
#pragma unroll 1
            for (; tt < pairs; ++tt) {
                int src = jb + 2 * tt + half;
                int srcc = min(src, e - 1);
                unsigned int bc = cols[srcc];
                float vv = bf16_bits_to_f32(vals[srcc]);
                float bv = (src < e) ? vv : 0.f;
                uint4 q = ((const uint4*)(xwb + (size_t)bc * D))[hl];
                FMA8(q, bv)
            }
        }

        // overflow entries (never in practice): half-0 lanes contribute
#pragma unroll 1
        for (int k = 0; k < nov; ++k) {
            unsigned long long rec = ovfl[k];
            if ((int)((rec >> 33) & 63u) == rl) {
                unsigned int bc = (unsigned int)(rec & 0x1FFFFu);
                float vv = bf16_bits_to_f32((unsigned short)((rec >> 17) & 0xFFFFu));
                float bv = (half == 0) ? vv : 0.f;
                uint4 q = ((const uint4*)(xwb + (size_t)bc * D))[hl];
                FMA8(q, bv)
            }
        }
#undef FMA8

        // combine even/odd halves (lane l and l^32 hold the same columns)
#pragma unroll
        for (int k = 0; k < 8; ++k) acc[k] += __shfl_xor(acc[k], 32);

        // redistribute: lane l writes cols 4l..4l+3 (source lane l>>1)
        const int sl = lane >> 1;
        const int par = lane & 1;
        float4 o;
        {
            float a0 = __shfl(acc[0], sl), c0 = __shfl(acc[4], sl);
            float a1 = __shfl(acc[1], sl), c1 = __shfl(acc[5], sl);
            float a2 = __shfl(acc[2], sl), c2 = __shfl(acc[6], sl);
            float a3 = __shfl(acc[3], sl), c3 = __shfl(acc[7], sl);
            o.x = par ? c0 : a0;
            o.y = par ? c1 : a1;
            o.z = par ? c2 : a2;
            o.w = par ? c3 : a3;
        }
        o.x = fmaxf(o.x, 0.f);
        o.y = fmaxf(o.y, 0.f);
        o.z = fmaxf(o.z, 0.f);
        o.w = fmaxf(o.w, 0.f);
        ((float4*)(out + (size_t)r * D))[lane] = o;
    }
}

extern "C" void kernel_launch(void* const* d_in, const int* in_sizes, int n_in,
                              void* d_out, int out_size, void* d_ws, size_t ws_size,
                              hipStream_t stream) {
    const float* x    = (const float*)d_in[0];
    const float* w    = (const float*)d_in[1];
    const int*   erow = (const int*)d_in[2];
    const int*   ecol = (const int*)d_in[3];
    const float* eval = (const float*)d_in[4];
    float* out = (float*)d_out;

    // ---- workspace layout (~89 MB) ----
    char* p = (char*)d_ws;
    auto align = [](size_t v) { return (v + 255) & ~(size_t)255; };

    unsigned short* xwb = (unsigned short*)p;                  // 51.2 MB
    p += align((size_t)N_NODES * D * sizeof(unsigned short));
    unsigned short* wsw = (unsigned short*)p;                  // 128 KiB
    p += align((size_t)D * D * sizeof(unsigned short));
    int* Cloc = (int*)p;                                       // 6.4 MB
    p += align((size_t)NBLK_F * CLOC_W * sizeof(int));
    unsigned short* Ctr = (unsigned short*)p;                  // 3.2 MB
    p += align((size_t)CLOC_W * NBLK_F * sizeof(unsigned short));
    unsigned long long* recs = (unsigned long long*)p;         // 25.6 MB
    p += align((size_t)NBLK_F * REC_STRIDE * sizeof(unsigned long long));

    convert_w_k<<<(D * D) / 256, 256, 0, stream>>>(w, wsw);
    gemm_xw_k<<<(N_NODES + 127) / 128, 512, 0, stream>>>(x, wsw, xwb);
    bfill_k<<<NBLK_F, 512, 0, stream>>>(erow, ecol, eval, Cloc, recs);
    tr_k<<<TRT_B * TRT_K, 256, 0, stream>>>(Cloc, Ctr);
    baggr_k<<<NB3, 256, 0, stream>>>(xwb, Ctr, recs, out);
}

// Round 11
// 488.070 us; speedup vs baseline: 1.0171x; 1.0171x over previous
//
#include <hip/hip_runtime.h>
#include <hip/hip_bf16.h>

#define N_NODES 100000
#define N_EDGES 3200000
#define D 256

// ---- buckets: 64 rows each ----
#define RSH3 6
#define RPB3 64
#define NB3 ((N_NODES + RPB3 - 1) / RPB3)          // 1563
// ---- fill chunking (block-major recs layout, 512 chunks) ----
#define FILL_CH 6250                                // edges per fill block
#define NBLK_F 512                                  // 512*6250 = 3.2M exactly
#define CLOC_W (NB3 + 1)                            // 1564
// ---- fused sort+aggregate caps ----
#define RCAP 12                                     // recs/thread in regs
#define SCAP 3072                                   // = RCAP*256; sorted LDS capacity
#define OCAP 64                                     // overflow side-buffer

typedef __attribute__((ext_vector_type(8))) short short8;   // 8 bf16 (4 VGPRs)
typedef __attribute__((ext_vector_type(4))) float floatx4;  // MFMA C/D
typedef __attribute__((ext_vector_type(4))) float fltx4;    // NT-capable float4
typedef __attribute__((ext_vector_type(4))) unsigned int uintx4;  // NT-capable uint4

__device__ __forceinline__ unsigned short f32_to_bf16_rne(float f) {
    unsigned int u = __float_as_uint(f);
    u += 0x7FFFu + ((u >> 16) & 1u);
    return (unsigned short)(u >> 16);
}
__device__ __forceinline__ float bf16_bits_to_f32(unsigned short b) {
    return __uint_as_float(((unsigned int)b) << 16);
}
__device__ __forceinline__ float blo(unsigned int x) { return __uint_as_float(x << 16); }
__device__ __forceinline__ float bhi(unsigned int x) { return __uint_as_float(x & 0xFFFF0000u); }

// ---------------- W (fp32 [K][N]) -> bf16 MFMA-B-fragment order --------------
__global__ __launch_bounds__(256) void convert_w_k(const float* __restrict__ w,
                                                   unsigned short* __restrict__ wsw) {
    int t = blockIdx.x * 256 + threadIdx.x;
    int j     = t & 7;
    int lane  = (t >> 3) & 63;
    int kstep = (t >> 9) & 7;
    int ntile = t >> 12;
    int k = kstep * 32 + (lane >> 4) * 8 + j;
    int n = ntile * 16 + (lane & 15);
    wsw[t] = f32_to_bf16_rne(w[k * D + n]);
}

// ---------------- xw = x @ W (bf16 MFMA), output bf16 ------------------------
// x is read once -> non-temporal loads (keep L3 for xwb). xwb writes stay
// cached (they are the gather table for baggr).
__global__ __launch_bounds__(512) void gemm_xw_k(const float* __restrict__ x,
                                                 const unsigned short* __restrict__ wsw,
                                                 unsigned short* __restrict__ xwb) {
    __shared__ uint4 wlds[8192];  // 128 KiB swizzled bf16 W
    const int tid = threadIdx.x;
#pragma unroll
    for (int i = 0; i < 16; ++i) {
        int idx = i * 512 + tid;
        wlds[idx] = ((const uint4*)wsw)[idx];
    }
    __syncthreads();

    const int lane = tid & 63;
    const int wave = tid >> 6;            // 0..7
    const int q    = lane >> 4;
    const int ml   = lane & 15;
    const long rowBase = (long)blockIdx.x * 128 + wave * 16;
    long arow = rowBase + ml;
    if (arow >= N_NODES) arow = 0;
    const float* xr = x + arow * (long)D;

    floatx4 acc[16];
#pragma unroll
    for (int i = 0; i < 16; ++i) acc[i] = (floatx4){0.f, 0.f, 0.f, 0.f};

    const short8* wfrag = (const short8*)wlds;

#pragma unroll
    for (int ks = 0; ks < 8; ++ks) {
        const fltx4 a0 = __builtin_nontemporal_load((const fltx4*)(xr + ks * 32 + q * 8));
        const fltx4 a1 = __builtin_nontemporal_load((const fltx4*)(xr + ks * 32 + q * 8 + 4));
        short8 af;
        af[0] = (short)f32_to_bf16_rne(a0[0]);
        af[1] = (short)f32_to_bf16_rne(a0[1]);
        af[2] = (short)f32_to_bf16_rne(a0[2]);
        af[3] = (short)f32_to_bf16_rne(a0[3]);
        af[4] = (short)f32_to_bf16_rne(a1[0]);
        af[5] = (short)f32_to_bf16_rne(a1[1]);
        af[6] = (short)f32_to_bf16_rne(a1[2]);
        af[7] = (short)f32_to_bf16_rne(a1[3]);
#pragma unroll
        for (int nt = 0; nt < 16; ++nt) {
            acc[nt] = __builtin_amdgcn_mfma_f32_16x16x32_bf16(
                af, wfrag[(nt * 8 + ks) * 64 + lane], acc[nt], 0, 0, 0);
        }
    }

#pragma unroll
    for (int nt = 0; nt < 16; ++nt) {
#pragma unroll
        for (int r = 0; r < 4; ++r) {
            long orow = rowBase + q * 4 + r;
            if (orow < N_NODES)
                xwb[orow * (long)D + nt * 16 + ml] = f32_to_bf16_rne(acc[nt][r]);
        }
    }
}

// ---------------- single-kernel build: LDS-staged sort, block-major ----------
// erow read twice -> cached; ecol/eval once -> non-temporal; recs flush is
// stream-once -> non-temporal b128 stores.
__global__ __launch_bounds__(512) void bfill_k(const int* __restrict__ erow,
                                               const int* __restrict__ ecol,
                                               const float* __restrict__ eval,
                                               int* __restrict__ Cloc,
                                               unsigned long long* __restrict__ recs) {
    __shared__ unsigned long long lrec[FILL_CH];   // 50 KB
    __shared__ int h[NB3];
    __shared__ int cur[NB3];
    __shared__ int wsum[8];
    const int tid = threadIdx.x;
    const int blk = blockIdx.x;
    const int s = blk * FILL_CH;
    const int e = min(s + FILL_CH, N_EDGES);
    const int n = e - s;

    for (int i = tid; i < NB3; i += 512) h[i] = 0;
    __syncthreads();

    // bucket histogram
    for (int i = s + tid; i < e; i += 512) atomicAdd(&h[erow[i] >> RSH3], 1);
    __syncthreads();

    // scan NB3 bins (4/thread) -> cur (local excl prefix) + write Cloc row
    {
        const int b0 = 4 * tid;
        int v0 = (b0     < NB3) ? h[b0]     : 0;
        int v1 = (b0 + 1 < NB3) ? h[b0 + 1] : 0;
        int v2 = (b0 + 2 < NB3) ? h[b0 + 2] : 0;
        int v3 = (b0 + 3 < NB3) ? h[b0 + 3] : 0;
        int s4 = v0 + v1 + v2 + v3;
        const int lane = tid & 63;
        const int wv = tid >> 6;
        int x = s4;
#pragma unroll
        for (int d = 1; d < 64; d <<= 1) {
            int u = __shfl_up(x, d);
            if (lane >= d) x += u;
        }
        if (lane == 63) wsum[wv] = x;
        __syncthreads();
        if (wv == 0) {
            int y = (lane < 8) ? wsum[lane] : 0;
#pragma unroll
            for (int d = 1; d < 8; d <<= 1) {
                int u = __shfl_up(y, d);
                if (lane >= d) y += u;
            }
            if (lane < 8) wsum[lane] = y;
        }
        __syncthreads();
        int excl = x - s4 + ((wv > 0) ? wsum[wv - 1] : 0);
        int* crow = Cloc + (size_t)blk * CLOC_W;
        if (b0     < NB3) { cur[b0]     = excl;                crow[b0]     = excl; }
        if (b0 + 1 < NB3) { cur[b0 + 1] = excl + v0;           crow[b0 + 1] = excl + v0; }
        if (b0 + 2 < NB3) { cur[b0 + 2] = excl + v0 + v1;      crow[b0 + 2] = excl + v0 + v1; }
        if (b0 + 3 < NB3) { cur[b0 + 3] = excl + v0 + v1 + v2; crow[b0 + 3] = excl + v0 + v1 + v2; }
        if (tid == 0) crow[NB3] = n;
    }
    __syncthreads();

    // scatter into LDS (bucket-sorted within block)
    for (int i = s + tid; i < e; i += 512) {
        int r = erow[i];
        int b = r >> RSH3;
        int c = __builtin_nontemporal_load(&ecol[i]);
        float v = __builtin_nontemporal_load(&eval[i]);
        unsigned long long rec =
            ((unsigned long long)(r & (RPB3 - 1)) << 33) |
            ((unsigned long long)f32_to_bf16_rne(v) << 17) |
            (unsigned int)c;
        int pos = atomicAdd(&cur[b], 1);
        lrec[pos] = rec;
    }
    __syncthreads();

    // flush: vectorized (2 recs per op), non-temporal, private region
    unsigned long long* grow = recs + (size_t)blk * FILL_CH;   // 50000B stride, 16B-aligned
    {
        const uintx4* lv = (const uintx4*)lrec;
        uintx4* gv = (uintx4*)grow;
        const int np = n >> 1;
        for (int i = tid; i < np; i += 512)
            __builtin_nontemporal_store(lv[i], &gv[i]);
        if ((n & 1) && tid == 0) grow[n - 1] = lrec[n - 1];
    }
}

// ---------------- transpose Cloc (u32 [NBLK_F][CLOC_W]) -> Ctr u16 -----------
#define TRT_B ((CLOC_W + 63) / 64)                  // 25
#define TRT_K (NBLK_F / 64)                         // 8
__global__ __launch_bounds__(256) void tr_k(const int* __restrict__ Cloc,
                                            unsigned short* __restrict__ Ctr) {
    __shared__ unsigned short tile[64][65];
    const int bt = blockIdx.x % TRT_B;
    const int kt = blockIdx.x / TRT_B;
#pragma unroll
    for (int i = 0; i < 16; ++i) {
        int r = i * 4 + (threadIdx.x >> 6);          // row within blk-tile
        int c = threadIdx.x & 63;                    // col within b-tile
        int blk = kt * 64 + r;
        int b   = bt * 64 + c;
        tile[r][c] = (blk < NBLK_F && b < CLOC_W)
                         ? (unsigned short)Cloc[(size_t)blk * CLOC_W + b] : (unsigned short)0;
    }
    __syncthreads();
#pragma unroll
    for (int i = 0; i < 16; ++i) {
        int r = i * 4 + (threadIdx.x >> 6);          // row within b-tile -> Ctr row
        int c = threadIdx.x & 63;                    // col within blk-tile -> Ctr col
        int b   = bt * 64 + r;
        int blk = kt * 64 + c;
        if (b < CLOC_W && blk < NBLK_F)
            Ctr[(size_t)b * NBLK_F + blk] = tile[c][r];
    }
}

// ---------------- binary-search fallback (rare overflow path only) -----------
__device__ __forceinline__ unsigned long long fetch_rec(
    const unsigned long long* __restrict__ recs,
    const unsigned short* __restrict__ S,
    const unsigned short* __restrict__ P, int i) {
    int lo = 0, hi = NBLK_F;
#pragma unroll
    for (int it = 0; it < 9; ++it) {               // 512 -> 1 in 9 halvings
        int mid = (lo + hi) >> 1;
        if ((int)P[mid] <= i) lo = mid; else hi = mid;
    }
    return recs[(size_t)lo * FILL_CH + (int)S[lo] + (i - (int)P[lo])];
}

// ---------------- fused per-bucket sort + segment reduce ---------------------
// recs reads and out writes are stream-once -> non-temporal; xwb gather reads
// stay cached (the array we want resident in L2/L3).
__global__ __launch_bounds__(256) void baggr_k(const unsigned short* __restrict__ xwb,
                                               const unsigned short* __restrict__ Ctr,
                                               const unsigned long long* __restrict__ recs,
                                               float* __restrict__ out) {
    __shared__ unsigned int   cols[SCAP];          // 12 KiB (scratch: index map, then sorted cols)
    __shared__ unsigned short vals[SCAP];          // 6 KiB
    __shared__ unsigned long long ovfl[OCAP];
    __shared__ unsigned short S[NBLK_F];
    __shared__ unsigned short L[NBLK_F];
    __shared__ unsigned short P[NBLK_F + 1];
    __shared__ int hist[RPB3];
    __shared__ int cur[RPB3];
    __shared__ int wsum4[4];
    __shared__ int novf;
    const int t = threadIdx.x;
    const int b = blockIdx.x;

    if (t < RPB3) hist[t] = 0;
    if (t == 0) novf = 0;
    // stage this bucket's run table: two contiguous u16 rows of Ctr
    {
        const unsigned short* Sb = Ctr + (size_t)b * NBLK_F;
        const unsigned short* Eb = Ctr + (size_t)(b + 1) * NBLK_F;
        for (int j = t; j < NBLK_F; j += 256) {
            unsigned short a = Sb[j];
            S[j] = a;
            L[j] = (unsigned short)(Eb[j] - a);
        }
    }
    __syncthreads();

    // scan run lengths -> P (exclusive), 2/thread over NBLK_F entries
    {
        const int j0 = 2 * t, j1 = 2 * t + 1;
        int v0 = (j0 < NBLK_F) ? (int)L[j0] : 0;
        int v1 = (j1 < NBLK_F) ? (int)L[j1] : 0;
        int sv = v0 + v1;
        const int lane = t & 63;
        const int wv = t >> 6;
        int x = sv;
#pragma unroll
        for (int d = 1; d < 64; d <<= 1) {
            int u = __shfl_up(x, d);
            if (lane >= d) x += u;
        }
        if (lane == 63) wsum4[wv] = x;
        __syncthreads();
        if (wv == 0) {
            int y = (lane < 4) ? wsum4[lane] : 0;
#pragma unroll
            for (int d = 1; d < 4; d <<= 1) {
                int u = __shfl_up(y, d);
                if (lane >= d) y += u;
            }
            if (lane < 4) wsum4[lane] = y;
        }
        __syncthreads();
        int excl = x - sv + ((wv > 0) ? wsum4[wv - 1] : 0);
        if (j0 < NBLK_F) P[j0] = (unsigned short)excl;
        if (j1 < NBLK_F) P[j1] = (unsigned short)(excl + v0);
        if (j0 == NBLK_F - 1) P[NBLK_F] = (unsigned short)(excl + v0);
        if (j1 == NBLK_F - 1) P[NBLK_F] = (unsigned short)(excl + v0 + v1);
    }
    __syncthreads();
    const int nfull = (int)P[NBLK_F];

    // build direct index map in cols[] scratch: cols[flat i] = rec index in recs
    for (int j = t; j < NBLK_F; j += 256) {
        int p = (int)P[j];
        int len = (int)L[j];
        unsigned int base = (unsigned int)(j * FILL_CH + (int)S[j]);
        for (int k = 0; k < len; ++k) {
            int pp = p + k;
            if (pp < SCAP) cols[pp] = base + k;
        }
    }
    __syncthreads();

    // load recs into regs via the map (non-temporal: stream-once)
    unsigned long long myrec[RCAP];
#pragma unroll
    for (int k = 0; k < RCAP; ++k) {
        int i = k * 256 + t;                       // i < RCAP*256 == SCAP
        if (i < nfull) myrec[k] = __builtin_nontemporal_load(&recs[cols[i]]);
    }
#pragma unroll
    for (int k = 0; k < RCAP; ++k) {
        int i = k * 256 + t;
        if (i < nfull) atomicAdd(&hist[(int)((myrec[k] >> 33) & 63u)], 1);
    }
    for (int i = SCAP + t; i < nfull; i += 256)    // never in practice
        atomicAdd(&hist[(int)((fetch_rec(recs, S, P, i) >> 33) & 63u)], 1);
    __syncthreads();

    // exclusive scan of 64 row bins (wave 0)
    if (t < 64) {
        int v = hist[t];
        int x = v;
#pragma unroll
        for (int d = 1; d < 64; d <<= 1) {
            int u = __shfl_up(x, d);
            if (t >= d) x += u;
        }
        cur[t] = x - v;
    }
    __syncthreads();

    // scatter into sorted split arrays (overwrites the cols[] scratch)
#pragma unroll
    for (int k = 0; k < RCAP; ++k) {
        int i = k * 256 + t;
        if (i < nfull) {
            unsigned long long rec = myrec[k];
            int rl = (int)((rec >> 33) & 63u);
            int pos = atomicAdd(&cur[rl], 1);
            if (pos < SCAP) {
                cols[pos] = (unsigned int)(rec & 0x1FFFFu);
                vals[pos] = (unsigned short)((rec >> 17) & 0xFFFFu);
            } else {
                int o = atomicAdd(&novf, 1);
                if (o < OCAP) ovfl[o] = rec;
            }
        }
    }
    for (int i = SCAP + t; i < nfull; i += 256) {  // never in practice
        unsigned long long rec = fetch_rec(recs, S, P, i);
        int rl = (int)((rec >> 33) & 63u);
        int pos = atomicAdd(&cur[rl], 1);
        if (pos < SCAP) {
            cols[pos] = (unsigned int)(rec & 0x1FFFFu);
            vals[pos] = (unsigned short)((rec >> 17) & 0xFFFFu);
        } else {
            int o = atomicAdd(&novf, 1);
            if (o < OCAP) ovfl[o] = rec;
        }
    }
    __syncthreads();

    const int wave = t >> 6;
    const int lane = t & 63;
    const int half = lane >> 5;
    const int hl   = lane & 31;
    const int nov  = min(novf, OCAP);

#pragma unroll 1
    for (int rr = 0; rr < 16; ++rr) {
        const int rl = wave * 16 + rr;
        const int r = (b << RSH3) + rl;
        if (r >= N_NODES) break;
        const int e_ = cur[rl];
        const int s_ = e_ - hist[rl];
        const int e = min(e_, SCAP);
        const int s = min(s_, SCAP);

        float acc[8];
#pragma unroll
        for (int k = 0; k < 8; ++k) acc[k] = 0.f;

#pragma unroll 1
        for (int jb = s; jb < e; jb += 64) {
            const int cnt = min(64, e - jb);
            const int pairs = (cnt + 1) >> 1;
            const int hp = cnt >> 1;
            int tt = 0;

#define FMA8(qv, bv)                                                           \
            acc[0] += bv * blo(qv.x); acc[1] += bv * bhi(qv.x);                \
            acc[2] += bv * blo(qv.y); acc[3] += bv * bhi(qv.y);                \
            acc[4] += bv * blo(qv.z); acc[5] += bv * bhi(qv.z);                \
            acc[6] += bv * blo(qv.w); acc[7] += bv * bhi(qv.w);
#define SLOTL(ss, qv, bv)                                                      \
            {                                                                  \
                int src = jb + 2 * (tt + (ss)) + half;                         \
                unsigned int bc = cols[src];                                   \
                bv = bf16_bits_to_f32(vals[src]);                              \
                qv = ((const uint4*)(xwb + (size_t)bc * D))[hl];               \
            }

            // ---- 8-deep unmasked fast path (16 edges / iter) ----
#pragma unroll 1
            for (; tt + 8 <= hp; tt += 8) {
                uint4 q0, q1, q2, q3, q4, q5, q6, q7;
                float b0, b1, b2, b3, b4, b5, b6, b7;
                SLOTL(0, q0, b0) SLOTL(1, q1, b1) SLOTL(2, q2, b2) SLOTL(3, q3, b3)
                SLOTL(4, q4, b4) SLOTL(5, q5, b5) SLOTL(6, q6, b6) SLOTL(7, q7, b7)
                FMA8(q0, b0) FMA8(q1, b1) FMA8(q2, b2) FMA8(q3, b3)
                FMA8(q4, b4) FMA8(q5, b5) FMA8(q6, b6) FMA8(q7, b7)
            }
            // ---- 4-deep unmasked (8 edges) ----
            if (tt + 4 <= hp) {
                uint4 q0, q1, q2, q3;
                float b0, b1, b2, b3;
                SLOTL(0, q0, b0) SLOTL(1, q1, b1) SLOTL(2, q2, b2) SLOTL(3, q3, b3)
                FMA8(q0, b0) FMA8(q1, b1) FMA8(q2, b2) FMA8(q3, b3)
                tt += 4;
            }
#undef SLOTL
            // ---- masked scalar-pair tail ----
#pragma unroll 1
            for (; tt < pairs; ++tt) {
                int src = jb + 2 * tt + half;
                int srcc = min(src, e - 1);
                unsigned int bc = cols[srcc];
                float vv = bf16_bits_to_f32(vals[srcc]);
                float bv = (src < e) ? vv : 0.f;
                uint4 q = ((const uint4*)(xwb + (size_t)bc * D))[hl];
                FMA8(q, bv)
            }
        }

        // overflow entries (never in practice): half-0 lanes contribute
#pragma unroll 1
        for (int k = 0; k < nov; ++k) {
            unsigned long long rec = ovfl[k];
            if ((int)((rec >> 33) & 63u) == rl) {
                unsigned int bc = (unsigned int)(rec & 0x1FFFFu);
                float vv = bf16_bits_to_f32((unsigned short)((rec >> 17) & 0xFFFFu));
                float bv = (half == 0) ? vv : 0.f;
                uint4 q = ((const uint4*)(xwb + (size_t)bc * D))[hl];
                FMA8(q, bv)
            }
        }
#undef FMA8

        // combine even/odd halves (lane l and l^32 hold the same columns)
#pragma unroll
        for (int k = 0; k < 8; ++k) acc[k] += __shfl_xor(acc[k], 32);

        // redistribute: lane l writes cols 4l..4l+3 (source lane l>>1)
        const int sl = lane >> 1;
        const int par = lane & 1;
        fltx4 o;
        {
            float a0 = __shfl(acc[0], sl), c0 = __shfl(acc[4], sl);
            float a1 = __shfl(acc[1], sl), c1 = __shfl(acc[5], sl);
            float a2 = __shfl(acc[2], sl), c2 = __shfl(acc[6], sl);
            float a3 = __shfl(acc[3], sl), c3 = __shfl(acc[7], sl);
            o[0] = par ? c0 : a0;
            o[1] = par ? c1 : a1;
            o[2] = par ? c2 : a2;
            o[3] = par ? c3 : a3;
        }
        o[0] = fmaxf(o[0], 0.f);
        o[1] = fmaxf(o[1], 0.f);
        o[2] = fmaxf(o[2], 0.f);
        o[3] = fmaxf(o[3], 0.f);
        __builtin_nontemporal_store(o, &((fltx4*)(out + (size_t)r * D))[lane]);
    }
}

extern "C" void kernel_launch(void* const* d_in, const int* in_sizes, int n_in,
                              void* d_out, int out_size, void* d_ws, size_t ws_size,
                              hipStream_t stream) {
    const float* x    = (const float*)d_in[0];
    const float* w    = (const float*)d_in[1];
    const int*   erow = (const int*)d_in[2];
    const int*   ecol = (const int*)d_in[3];
    const float* eval = (const float*)d_in[4];
    float* out = (float*)d_out;

    // ---- workspace layout (~82 MB) ----
    char* p = (char*)d_ws;
    auto align = [](size_t v) { return (v + 255) & ~(size_t)255; };

    unsigned short* xwb = (unsigned short*)p;                  // 51.2 MB
    p += align((size_t)N_NODES * D * sizeof(unsigned short));
    unsigned short* wsw = (unsigned short*)p;                  // 128 KiB
    p += align((size_t)D * D * sizeof(unsigned short));
    int* Cloc = (int*)p;                                       // 3.2 MB
    p += align((size_t)NBLK_F * CLOC_W * sizeof(int));
    unsigned short* Ctr = (unsigned short*)p;                  // 1.6 MB
    p += align((size_t)CLOC_W * NBLK_F * sizeof(unsigned short));
    unsigned long long* recs = (unsigned long long*)p;         // 25.6 MB
    p += align((size_t)NBLK_F * FILL_CH * sizeof(unsigned long long));

    convert_w_k<<<(D * D) / 256, 256, 0, stream>>>(w, wsw);
    gemm_xw_k<<<(N_NODES + 127) / 128, 512, 0, stream>>>(x, wsw, xwb);
    bfill_k<<<NBLK_F, 512, 0, stream>>>(erow, ecol, eval, Cloc, recs);
    tr_k<<<TRT_B * TRT_K, 256, 0, stream>>>(Cloc, Ctr);
    baggr_k<<<NB3, 256, 0, stream>>>(xwb, Ctr, recs, out);
}